// Round 9
// baseline (1540.138 us; speedup 1.0000x reference)
//
#include <hip/hip_runtime.h>
#include <hip/hip_fp16.h>

#define N_NODES 100000
#define N_EDGES 1600000
#define HDIM 64
#define NPB 256                                  // nodes per bucket (pow2)
#define NPB_SHIFT 8
#define NBUCK ((N_NODES + NPB - 1) / NPB)        // 391
#define NCHUNK 256                               // phase-A blocks (== blockDim of chunk scan)
#define CHUNK (N_EDGES / NCHUNK)                 // 6250 edges/block

// ---------------- K1: per-chunk bucket histograms -> global (no global atomics) ----------------
__global__ void hist_kernel(const int* __restrict__ src, const int* __restrict__ dst,
                            int* __restrict__ hbD, int* __restrict__ hbS) {
    __shared__ int hD[NBUCK], hS[NBUCK];
    int t = threadIdx.x, blk = blockIdx.x;
    for (int i = t; i < NBUCK; i += 256) { hD[i] = 0; hS[i] = 0; }
    __syncthreads();
    int e0 = blk * CHUNK;
    for (int i = t; i < CHUNK; i += 256) {
        atomicAdd(&hD[dst[e0 + i] >> NPB_SHIFT], 1);
        atomicAdd(&hS[src[e0 + i] >> NPB_SHIFT], 1);
    }
    __syncthreads();
    for (int i = t; i < NBUCK; i += 256) {
        hbD[i * NCHUNK + blk] = hD[i];
        hbS[i * NCHUNK + blk] = hS[i];
    }
}

// ---------------- K2a: per-bucket scan across chunks -> chunk prefixes + bucket totals ----------------
__global__ void chunk_scan_kernel(const int* __restrict__ hbD, const int* __restrict__ hbS,
                                  int* __restrict__ pbD, int* __restrict__ pbS,
                                  int* __restrict__ totD, int* __restrict__ totS) {
    __shared__ int s[NCHUNK];
    int b = blockIdx.x, t = threadIdx.x;   // blockDim = NCHUNK
    int v = hbD[b * NCHUNK + t];
    s[t] = v;
    __syncthreads();
    for (int off = 1; off < NCHUNK; off <<= 1) {
        int x = (t >= off) ? s[t - off] : 0;
        __syncthreads(); s[t] += x; __syncthreads();
    }
    pbD[b * NCHUNK + t] = s[t] - v;
    if (t == NCHUNK - 1) totD[b] = s[t];
    __syncthreads();
    v = hbS[b * NCHUNK + t];
    s[t] = v;
    __syncthreads();
    for (int off = 1; off < NCHUNK; off <<= 1) {
        int x = (t >= off) ? s[t - off] : 0;
        __syncthreads(); s[t] += x; __syncthreads();
    }
    pbS[b * NCHUNK + t] = s[t] - v;
    if (t == NCHUNK - 1) totS[b] = s[t];
}

// ---------------- K2b: scan bucket totals -> bucket bases ----------------
__global__ void bucket_base_kernel(const int* __restrict__ totD, const int* __restrict__ totS,
                                   int* __restrict__ baseD, int* __restrict__ baseS) {
    __shared__ int s[512];
    int t = threadIdx.x;   // blockDim = 512
    int v = (t < NBUCK) ? totD[t] : 0;
    s[t] = v;
    __syncthreads();
    for (int off = 1; off < 512; off <<= 1) {
        int x = (t >= off) ? s[t - off] : 0;
        __syncthreads(); s[t] += x; __syncthreads();
    }
    if (t < NBUCK) baseD[t] = s[t] - v;
    __syncthreads();
    v = (t < NBUCK) ? totS[t] : 0;
    s[t] = v;
    __syncthreads();
    for (int off = 1; off < 512; off <<= 1) {
        int x = (t >= off) ? s[t - off] : 0;
        __syncthreads(); s[t] += x; __syncthreads();
    }
    if (t < NBUCK) baseS[t] = s[t] - v;
}

// ---------------- K3: place edges into bucket-partitioned staging (LDS cursors only) ----------------
// bufD entry: src | (local_dst << 17)   (src < 2^17, local_dst < 256)
__global__ void place_kernel(const int* __restrict__ src, const int* __restrict__ dst,
                             const int* __restrict__ baseD, const int* __restrict__ pbD,
                             const int* __restrict__ baseS, const int* __restrict__ pbS,
                             unsigned int* __restrict__ bufD, unsigned char* __restrict__ bufS) {
    __shared__ int curD[NBUCK], curS[NBUCK];
    int t = threadIdx.x, blk = blockIdx.x;
    for (int i = t; i < NBUCK; i += 256) {
        curD[i] = baseD[i] + pbD[i * NCHUNK + blk];
        curS[i] = baseS[i] + pbS[i * NCHUNK + blk];
    }
    __syncthreads();
    int e0 = blk * CHUNK;
    for (int i = t; i < CHUNK; i += 256) {
        int s = src[e0 + i], d = dst[e0 + i];
        int pd = atomicAdd(&curD[d >> NPB_SHIFT], 1);
        bufD[pd] = (unsigned)s | ((unsigned)(d & (NPB - 1)) << 17);
        int ps = atomicAdd(&curS[s >> NPB_SHIFT], 1);
        bufS[ps] = (unsigned char)(s & (NPB - 1));
    }
}

// ---------------- K4: per src-bucket: counts -> inv_out ----------------
__global__ void bucket_src_kernel(const unsigned char* __restrict__ bufS,
                                  const int* __restrict__ baseS, const int* __restrict__ totS,
                                  float* __restrict__ inv_out) {
    __shared__ int cnt[NPB];
    int b = blockIdx.x, t = threadIdx.x;   // blockDim = 256
    int ebase = baseS[b], ecnt = totS[b];
    cnt[t] = 0;
    __syncthreads();
    for (int i = t; i < ecnt; i += NPB)
        atomicAdd(&cnt[(int)bufS[ebase + i]], 1);
    __syncthreads();
    int node = b * NPB + t;
    if (node < N_NODES) inv_out[node] = rsqrtf((float)max(cnt[t], 1));
}

__device__ inline uint2 f4_to_h4(float4 a) {
    __half2 lo = __floats2half2_rn(a.x, a.y);
    __half2 hi = __floats2half2_rn(a.z, a.w);
    uint2 r;
    r.x = *(unsigned*)&lo;
    r.y = *(unsigned*)&hi;
    return r;
}

// ---------------- dense: hw(fp16) = (h * inv_out[:,None]) @ W  (32 rows/block) ----------------
__global__ void dense_kernel(const float* __restrict__ h, const float* __restrict__ inv_out,
                             const float* __restrict__ W, uint2* __restrict__ hw, int n) {
    __shared__ float Wlds[HDIM * HDIM];     // 16 KB
    __shared__ float Alds[32][HDIM + 1];    // 8.1 KB
    int t = threadIdx.x;
    int r0 = blockIdx.x * 32;

    for (int i = t; i < HDIM * HDIM / 4; i += 256)
        ((float4*)Wlds)[i] = ((const float4*)W)[i];

    for (int i = t; i < 512; i += 256) {    // 32 rows x 16 float4
        int r = i >> 4;
        int c4 = i & 15;
        int row = r0 + r;
        float4 v = make_float4(0.f, 0.f, 0.f, 0.f);
        float s = 0.f;
        if (row < n) {
            v = ((const float4*)h)[(long long)row * 16 + c4];
            s = inv_out[row];
        }
        Alds[r][c4 * 4 + 0] = v.x * s;
        Alds[r][c4 * 4 + 1] = v.y * s;
        Alds[r][c4 * 4 + 2] = v.z * s;
        Alds[r][c4 * 4 + 3] = v.w * s;
    }
    __syncthreads();

    int tx = t & 15;        // col quad
    int ty = t >> 4;        // 16 row-pairs
    float4 acc0 = make_float4(0.f, 0.f, 0.f, 0.f);
    float4 acc1 = acc0;

#pragma unroll 8
    for (int k = 0; k < HDIM; ++k) {
        float4 w = ((const float4*)(Wlds + k * HDIM))[tx];
        float a0 = Alds[2 * ty + 0][k];
        float a1 = Alds[2 * ty + 1][k];
        acc0.x = fmaf(a0, w.x, acc0.x); acc0.y = fmaf(a0, w.y, acc0.y);
        acc0.z = fmaf(a0, w.z, acc0.z); acc0.w = fmaf(a0, w.w, acc0.w);
        acc1.x = fmaf(a1, w.x, acc1.x); acc1.y = fmaf(a1, w.y, acc1.y);
        acc1.z = fmaf(a1, w.z, acc1.z); acc1.w = fmaf(a1, w.w, acc1.w);
    }

    int rb = r0 + 2 * ty;
    if (rb + 0 < n) hw[(long long)(rb + 0) * 16 + tx] = f4_to_h4(acc0);
    if (rb + 1 < n) hw[(long long)(rb + 1) * 16 + tx] = f4_to_h4(acc1);
}

// ---------------- fused bucket gather: out = relu(inv_in * sum hw[src] + b) ----------------
// One block per 256-node dst bucket. LDS fp32 accum tile (column-rotated to spread banks),
// 8 lanes per edge (16 B fp16 each), LDS float atomics, degree counted inline.
__global__ void __launch_bounds__(512, 1)
bucket_gather_kernel(const uint4* __restrict__ hw, const unsigned int* __restrict__ bufD,
                     const int* __restrict__ baseD, const int* __restrict__ totD,
                     const float* __restrict__ bias, float* __restrict__ out, int n) {
    __shared__ float accum[NPB * HDIM];      // 64 KB, row r at accum[r*64], cols rotated by r
    __shared__ int   cnt[NPB];
    __shared__ float inv[NPB];
    __shared__ float bias_l[HDIM];

    int b = blockIdx.x, t = threadIdx.x;     // blockDim = 512
    for (int i = t; i < NPB * HDIM / 4; i += 512)
        ((float4*)accum)[i] = make_float4(0.f, 0.f, 0.f, 0.f);
    if (t < NPB) cnt[t] = 0;
    if (t < HDIM) bias_l[t] = bias[t];
    __syncthreads();

    int ebase = baseD[b], ecnt = totD[b];
    int g = t >> 3, gl = t & 7;              // 64 edge-groups of 8 lanes

#pragma unroll 2
    for (int i = g; i < ecnt; i += 64) {
        unsigned en = bufD[ebase + i];
        int s  = (int)(en & 0x1FFFFu);
        int ld = (int)(en >> 17);
        uint4 u = hw[(long long)s * 8 + gl];
        float2 f0 = __half22float2(*(__half2*)&u.x);
        float2 f1 = __half22float2(*(__half2*)&u.y);
        float2 f2 = __half22float2(*(__half2*)&u.z);
        float2 f3 = __half22float2(*(__half2*)&u.w);
        float* rowp = accum + ld * HDIM;
        int c0 = (gl << 3) + ld;             // rotated base col
        atomicAdd(rowp + ((c0 + 0) & 63), f0.x);
        atomicAdd(rowp + ((c0 + 1) & 63), f0.y);
        atomicAdd(rowp + ((c0 + 2) & 63), f1.x);
        atomicAdd(rowp + ((c0 + 3) & 63), f1.y);
        atomicAdd(rowp + ((c0 + 4) & 63), f2.x);
        atomicAdd(rowp + ((c0 + 5) & 63), f2.y);
        atomicAdd(rowp + ((c0 + 6) & 63), f3.x);
        atomicAdd(rowp + ((c0 + 7) & 63), f3.y);
        if (gl == 0) atomicAdd(&cnt[ld], 1);
    }
    __syncthreads();
    if (t < NPB) inv[t] = rsqrtf((float)max(cnt[t], 1));
    __syncthreads();

    int nb = b * NPB;
    for (int i = t; i < NPB * HDIM; i += 512) {
        int r = i >> 6, c = i & 63;
        int node = nb + r;
        if (node < n) {
            float v = accum[r * HDIM + ((c + r) & 63)];
            out[(long long)node * HDIM + c] = fmaxf(fmaf(v, inv[r], bias_l[c]), 0.f);
        }
    }
}

extern "C" void kernel_launch(void* const* d_in, const int* in_sizes, int n_in,
                              void* d_out, int out_size, void* d_ws, size_t ws_size,
                              hipStream_t stream) {
    const float* features = (const float*)d_in[0];   // [N, 64]
    const float* W        = (const float*)d_in[1];   // [64, 64]
    const float* b        = (const float*)d_in[2];   // [64]
    const int*   src      = (const int*)d_in[3];     // [E]
    const int*   dst      = (const int*)d_in[4];     // [E]

    float* out = (float*)d_out;                      // [N, 64] — also inter-layer temp

    // workspace layout (4-byte words); ws_size = 256 MB, no overlays needed (~23 MB used)
    float* ws = (float*)d_ws;
    uint2* hw = (uint2*)ws;                                    // N*16 uint2 = 12.8 MB (fp16 rows)
    unsigned int*  bufD = (unsigned int*)(ws + (size_t)N_NODES * 32);   // E words (6.4 MB)
    unsigned char* bufS = (unsigned char*)(bufD + N_EDGES);             // E bytes (1.6 MB)
    float* inv_out = (float*)(bufS + N_EDGES);       // N
    int*   hbD     = (int*)(inv_out + N_NODES);      // NBUCK*NCHUNK
    int*   hbS     = hbD + NBUCK * NCHUNK;
    int*   pbD     = hbS + NBUCK * NCHUNK;
    int*   pbS     = pbD + NBUCK * NCHUNK;
    int*   totD    = pbS + NBUCK * NCHUNK;           // NBUCK
    int*   totS    = totD + NBUCK;                   // NBUCK
    int*   baseD   = totS + NBUCK;                   // NBUCK
    int*   baseS   = baseD + NBUCK;                  // NBUCK

    const int N = N_NODES;

    // bucket-sorted edge staging (zero global atomics)
    hist_kernel<<<NCHUNK, 256, 0, stream>>>(src, dst, hbD, hbS);
    chunk_scan_kernel<<<NBUCK, NCHUNK, 0, stream>>>(hbD, hbS, pbD, pbS, totD, totS);
    bucket_base_kernel<<<1, 512, 0, stream>>>(totD, totS, baseD, baseS);
    place_kernel<<<NCHUNK, 256, 0, stream>>>(src, dst, baseD, pbD, baseS, pbS, bufD, bufS);
    bucket_src_kernel<<<NBUCK, NPB, 0, stream>>>(bufS, baseS, totS, inv_out);

    int dense_blocks = (N + 31) / 32;

    // layer 1: features -> hw(fp16) -> out
    dense_kernel<<<dense_blocks, 256, 0, stream>>>(features, inv_out, W, hw, N);
    bucket_gather_kernel<<<NBUCK, 512, 0, stream>>>((const uint4*)hw, bufD, baseD, totD, b, out, N);

    // layer 2: out -> hw(fp16) -> out
    dense_kernel<<<dense_blocks, 256, 0, stream>>>(out, inv_out, W, hw, N);
    bucket_gather_kernel<<<NBUCK, 512, 0, stream>>>((const uint4*)hw, bufD, baseD, totD, b, out, N);
}

// Round 10
// 247.569 us; speedup vs baseline: 6.2211x; 6.2211x over previous
//
#include <hip/hip_runtime.h>
#include <hip/hip_fp16.h>

#define N_NODES 100000
#define N_EDGES 1600000
#define HDIM 64
#define NPB 512                                  // nodes per bucket (pow2)
#define NPB_SHIFT 9
#define NBUCK ((N_NODES + NPB - 1) / NPB)        // 196
#define NCHUNK 512                               // phase-A blocks (== blockDim of chunk scan)
#define CHUNK (N_EDGES / NCHUNK)                 // 3125 edges/block

// ---------------- K1: per-chunk bucket histograms -> global (no global atomics) ----------------
__global__ void hist_kernel(const int* __restrict__ src, const int* __restrict__ dst,
                            int* __restrict__ hbD, int* __restrict__ hbS) {
    __shared__ int hD[NBUCK], hS[NBUCK];
    int t = threadIdx.x, blk = blockIdx.x;
    for (int i = t; i < NBUCK; i += 256) { hD[i] = 0; hS[i] = 0; }
    __syncthreads();
    int e0 = blk * CHUNK;
    for (int i = t; i < CHUNK; i += 256) {
        atomicAdd(&hD[dst[e0 + i] >> NPB_SHIFT], 1);
        atomicAdd(&hS[src[e0 + i] >> NPB_SHIFT], 1);
    }
    __syncthreads();
    for (int i = t; i < NBUCK; i += 256) {
        hbD[i * NCHUNK + blk] = hD[i];
        hbS[i * NCHUNK + blk] = hS[i];
    }
}

// ---------------- K2a: per-bucket scan across chunks -> chunk prefixes + bucket totals ----------------
__global__ void chunk_scan_kernel(const int* __restrict__ hbD, const int* __restrict__ hbS,
                                  int* __restrict__ pbD, int* __restrict__ pbS,
                                  int* __restrict__ totD, int* __restrict__ totS) {
    __shared__ int s[NCHUNK];
    int b = blockIdx.x, t = threadIdx.x;   // blockDim = NCHUNK
    int v = hbD[b * NCHUNK + t];
    s[t] = v;
    __syncthreads();
    for (int off = 1; off < NCHUNK; off <<= 1) {
        int x = (t >= off) ? s[t - off] : 0;
        __syncthreads(); s[t] += x; __syncthreads();
    }
    pbD[b * NCHUNK + t] = s[t] - v;
    if (t == NCHUNK - 1) totD[b] = s[t];
    __syncthreads();
    v = hbS[b * NCHUNK + t];
    s[t] = v;
    __syncthreads();
    for (int off = 1; off < NCHUNK; off <<= 1) {
        int x = (t >= off) ? s[t - off] : 0;
        __syncthreads(); s[t] += x; __syncthreads();
    }
    pbS[b * NCHUNK + t] = s[t] - v;
    if (t == NCHUNK - 1) totS[b] = s[t];
}

// ---------------- K2b: scan bucket totals -> bucket bases ----------------
__global__ void bucket_base_kernel(const int* __restrict__ totD, const int* __restrict__ totS,
                                   int* __restrict__ baseD, int* __restrict__ baseS) {
    __shared__ int s[256];
    int t = threadIdx.x;
    int v = (t < NBUCK) ? totD[t] : 0;
    s[t] = v;
    __syncthreads();
    for (int off = 1; off < 256; off <<= 1) {
        int x = (t >= off) ? s[t - off] : 0;
        __syncthreads(); s[t] += x; __syncthreads();
    }
    if (t < NBUCK) baseD[t] = s[t] - v;
    __syncthreads();
    v = (t < NBUCK) ? totS[t] : 0;
    s[t] = v;
    __syncthreads();
    for (int off = 1; off < 256; off <<= 1) {
        int x = (t >= off) ? s[t - off] : 0;
        __syncthreads(); s[t] += x; __syncthreads();
    }
    if (t < NBUCK) baseS[t] = s[t] - v;
}

// ---------------- K3: place edges into bucket-partitioned staging (LDS cursors only) ----------------
// bufD entry: src | (local_dst << 17)   (src < 2^17, local_dst < 512)
__global__ void place_kernel(const int* __restrict__ src, const int* __restrict__ dst,
                             const int* __restrict__ baseD, const int* __restrict__ pbD,
                             const int* __restrict__ baseS, const int* __restrict__ pbS,
                             unsigned int* __restrict__ bufD, unsigned short* __restrict__ bufS) {
    __shared__ int curD[NBUCK], curS[NBUCK];
    int t = threadIdx.x, blk = blockIdx.x;
    for (int i = t; i < NBUCK; i += 256) {
        curD[i] = baseD[i] + pbD[i * NCHUNK + blk];
        curS[i] = baseS[i] + pbS[i * NCHUNK + blk];
    }
    __syncthreads();
    int e0 = blk * CHUNK;
    for (int i = t; i < CHUNK; i += 256) {
        int s = src[e0 + i], d = dst[e0 + i];
        int pd = atomicAdd(&curD[d >> NPB_SHIFT], 1);
        bufD[pd] = (unsigned)s | ((unsigned)(d & (NPB - 1)) << 17);
        int ps = atomicAdd(&curS[s >> NPB_SHIFT], 1);
        bufS[ps] = (unsigned short)(s & (NPB - 1));
    }
}

// ---------------- K4: per dst-bucket: counts -> offsets/inv_in, place csr_src ----------------
__global__ void bucket_dst_kernel(const unsigned int* __restrict__ bufD,
                                  const int* __restrict__ baseD, const int* __restrict__ totD,
                                  int* __restrict__ csr_src, int* __restrict__ offsets,
                                  float* __restrict__ inv_in) {
    __shared__ int cnt[NPB], pre[NPB], cur[NPB];
    int b = blockIdx.x, t = threadIdx.x;   // blockDim = 512
    int ebase = baseD[b], ecnt = totD[b];
    cnt[t] = 0;
    __syncthreads();
    for (int i = t; i < ecnt; i += NPB)
        atomicAdd(&cnt[bufD[ebase + i] >> 17], 1);
    __syncthreads();
    int v = cnt[t];
    pre[t] = v;
    __syncthreads();
    for (int off = 1; off < NPB; off <<= 1) {
        int x = (t >= off) ? pre[t - off] : 0;
        __syncthreads(); pre[t] += x; __syncthreads();
    }
    int excl = pre[t] - v;
    cur[t] = excl;
    int node = b * NPB + t;
    if (node < N_NODES) {
        offsets[node] = ebase + excl;
        inv_in[node] = rsqrtf((float)max(v, 1));
    } else if (node == N_NODES) {
        offsets[N_NODES] = N_EDGES;
    }
    __syncthreads();
    for (int i = t; i < ecnt; i += NPB) {
        unsigned int en = bufD[ebase + i];
        int l = (int)(en >> 17);
        int pos = atomicAdd(&cur[l], 1);
        csr_src[ebase + pos] = (int)(en & 0x1FFFFu);
    }
}

// ---------------- K5: per src-bucket: counts -> inv_out ----------------
__global__ void bucket_src_kernel(const unsigned short* __restrict__ bufS,
                                  const int* __restrict__ baseS, const int* __restrict__ totS,
                                  float* __restrict__ inv_out) {
    __shared__ int cnt[NPB];
    int b = blockIdx.x, t = threadIdx.x;   // blockDim = 512
    int ebase = baseS[b], ecnt = totS[b];
    cnt[t] = 0;
    __syncthreads();
    for (int i = t; i < ecnt; i += NPB)
        atomicAdd(&cnt[(int)bufS[ebase + i]], 1);
    __syncthreads();
    int node = b * NPB + t;
    if (node < N_NODES) inv_out[node] = rsqrtf((float)max(cnt[t], 1));
}

__device__ inline uint2 f4_to_h4(float4 a) {
    __half2 lo = __floats2half2_rn(a.x, a.y);
    __half2 hi = __floats2half2_rn(a.z, a.w);
    uint2 r;
    r.x = *(unsigned*)&lo;
    r.y = *(unsigned*)&hi;
    return r;
}

// ---------------- dense: hw(fp16) = (h * inv_out[:,None]) @ W  (32 rows/block) ----------------
__global__ void dense_kernel(const float* __restrict__ h, const float* __restrict__ inv_out,
                             const float* __restrict__ W, uint2* __restrict__ hw, int n) {
    __shared__ float Wlds[HDIM * HDIM];     // 16 KB
    __shared__ float Alds[32][HDIM + 1];    // 8.1 KB
    int t = threadIdx.x;
    int r0 = blockIdx.x * 32;

    for (int i = t; i < HDIM * HDIM / 4; i += 256)
        ((float4*)Wlds)[i] = ((const float4*)W)[i];

    for (int i = t; i < 512; i += 256) {    // 32 rows x 16 float4
        int r = i >> 4;
        int c4 = i & 15;
        int row = r0 + r;
        float4 v = make_float4(0.f, 0.f, 0.f, 0.f);
        float s = 0.f;
        if (row < n) {
            v = ((const float4*)h)[(long long)row * 16 + c4];
            s = inv_out[row];
        }
        Alds[r][c4 * 4 + 0] = v.x * s;
        Alds[r][c4 * 4 + 1] = v.y * s;
        Alds[r][c4 * 4 + 2] = v.z * s;
        Alds[r][c4 * 4 + 3] = v.w * s;
    }
    __syncthreads();

    int tx = t & 15;        // col quad
    int ty = t >> 4;        // 16 row-pairs
    float4 acc0 = make_float4(0.f, 0.f, 0.f, 0.f);
    float4 acc1 = acc0;

#pragma unroll 8
    for (int k = 0; k < HDIM; ++k) {
        float4 w = ((const float4*)(Wlds + k * HDIM))[tx];
        float a0 = Alds[2 * ty + 0][k];
        float a1 = Alds[2 * ty + 1][k];
        acc0.x = fmaf(a0, w.x, acc0.x); acc0.y = fmaf(a0, w.y, acc0.y);
        acc0.z = fmaf(a0, w.z, acc0.z); acc0.w = fmaf(a0, w.w, acc0.w);
        acc1.x = fmaf(a1, w.x, acc1.x); acc1.y = fmaf(a1, w.y, acc1.y);
        acc1.z = fmaf(a1, w.z, acc1.z); acc1.w = fmaf(a1, w.w, acc1.w);
    }

    int rb = r0 + 2 * ty;
    if (rb + 0 < n) hw[(long long)(rb + 0) * 16 + tx] = f4_to_h4(acc0);
    if (rb + 1 < n) hw[(long long)(rb + 1) * 16 + tx] = f4_to_h4(acc1);
}

// ---------------- gather: out = relu(inv_in * sum_{in-edges} hw[src] + b) ----------------
// one 8-lane group per dst row (8 rows/wave, 32 rows/block); lane = 16B slice of the row.
// Next-batch index prefetch keeps the csr_src load off the critical chain.
__global__ void gather_kernel(const uint4* __restrict__ hw, const float* __restrict__ inv_in,
                              const int* __restrict__ offsets, const int* __restrict__ csr_src,
                              const float* __restrict__ bias, float* __restrict__ out, int n) {
    int t = threadIdx.x;
    int wave = t >> 6, lane = t & 63;
    int g = lane >> 3, gl = lane & 7;          // group 0..7, lane-in-group 0..7
    int row = blockIdx.x * 32 + wave * 8 + g;  // N = 3125 * 32 exactly
    if (row >= n) return;

    float acc0 = 0.f, acc1 = 0.f, acc2 = 0.f, acc3 = 0.f;
    float acc4 = 0.f, acc5 = 0.f, acc6 = 0.f, acc7 = 0.f;

    int start = offsets[row];
    int end   = offsets[row + 1];
    int gbase = g << 3;

    int jb = start;
    int mm = end - jb; if (mm > 8) mm = 8;
    int sidx = (mm > 0 && gl < mm) ? csr_src[jb + gl] : 0;

    while (jb < end) {
        // prefetch next batch's indices
        int jb2 = jb + 8;
        int mm2 = end - jb2; if (mm2 > 8) mm2 = 8;
        int sidx2 = (jb2 < end && gl < mm2) ? csr_src[jb2 + gl] : 0;

        if (mm == 8) {
#pragma unroll
            for (int j = 0; j < 8; ++j) {
                int s = __shfl(sidx, gbase + j, 64);
                uint4 u = hw[(long long)s * 8 + gl];
                float2 f0 = __half22float2(*(__half2*)&u.x);
                float2 f1 = __half22float2(*(__half2*)&u.y);
                float2 f2 = __half22float2(*(__half2*)&u.z);
                float2 f3 = __half22float2(*(__half2*)&u.w);
                acc0 += f0.x; acc1 += f0.y; acc2 += f1.x; acc3 += f1.y;
                acc4 += f2.x; acc5 += f2.y; acc6 += f3.x; acc7 += f3.y;
            }
        } else {
            for (int j = 0; j < mm; ++j) {
                int s = __shfl(sidx, gbase + j, 64);
                uint4 u = hw[(long long)s * 8 + gl];
                float2 f0 = __half22float2(*(__half2*)&u.x);
                float2 f1 = __half22float2(*(__half2*)&u.y);
                float2 f2 = __half22float2(*(__half2*)&u.z);
                float2 f3 = __half22float2(*(__half2*)&u.w);
                acc0 += f0.x; acc1 += f0.y; acc2 += f1.x; acc3 += f1.y;
                acc4 += f2.x; acc5 += f2.y; acc6 += f3.x; acc7 += f3.y;
            }
        }
        jb = jb2; mm = mm2; sidx = sidx2;
    }

    float sc = inv_in[row];
    float4 b0 = ((const float4*)bias)[gl * 2 + 0];
    float4 b1 = ((const float4*)bias)[gl * 2 + 1];
    float4 r0, r1;
    r0.x = fmaxf(fmaf(acc0, sc, b0.x), 0.f);
    r0.y = fmaxf(fmaf(acc1, sc, b0.y), 0.f);
    r0.z = fmaxf(fmaf(acc2, sc, b0.z), 0.f);
    r0.w = fmaxf(fmaf(acc3, sc, b0.w), 0.f);
    r1.x = fmaxf(fmaf(acc4, sc, b1.x), 0.f);
    r1.y = fmaxf(fmaf(acc5, sc, b1.y), 0.f);
    r1.z = fmaxf(fmaf(acc6, sc, b1.z), 0.f);
    r1.w = fmaxf(fmaf(acc7, sc, b1.w), 0.f);
    ((float4*)out)[(long long)row * 16 + gl * 2 + 0] = r0;
    ((float4*)out)[(long long)row * 16 + gl * 2 + 1] = r1;
}

extern "C" void kernel_launch(void* const* d_in, const int* in_sizes, int n_in,
                              void* d_out, int out_size, void* d_ws, size_t ws_size,
                              hipStream_t stream) {
    const float* features = (const float*)d_in[0];   // [N, 64]
    const float* W        = (const float*)d_in[1];   // [64, 64]
    const float* b        = (const float*)d_in[2];   // [64]
    const int*   src      = (const int*)d_in[3];     // [E]
    const int*   dst      = (const int*)d_in[4];     // [E]

    float* out = (float*)d_out;                      // [N, 64] — also inter-layer temp

    // workspace layout (4-byte words); ~40 MB of the 256 MB ws
    float* ws = (float*)d_ws;
    uint2* hw = (uint2*)ws;                                             // N*16 uint2 = 12.8 MB
    unsigned int*   bufD = (unsigned int*)(ws + (size_t)N_NODES * 32);  // E words (6.4 MB)
    unsigned short* bufS = (unsigned short*)(bufD + N_EDGES);           // E u16   (3.2 MB)
    float* inv_out = (float*)(bufS + N_EDGES);       // N
    float* inv_in  = inv_out + N_NODES;              // N
    int*   offsets = (int*)(inv_in + N_NODES);       // N+1
    int*   csr_src = offsets + N_NODES + 1;          // E
    int*   hbD     = csr_src + N_EDGES;              // NBUCK*NCHUNK
    int*   hbS     = hbD + NBUCK * NCHUNK;
    int*   pbD     = hbS + NBUCK * NCHUNK;
    int*   pbS     = pbD + NBUCK * NCHUNK;
    int*   totD    = pbS + NBUCK * NCHUNK;           // NBUCK
    int*   totS    = totD + NBUCK;                   // NBUCK
    int*   baseD   = totS + NBUCK;                   // NBUCK
    int*   baseS   = baseD + NBUCK;                  // NBUCK

    const int N = N_NODES;

    // CSR + degrees via bucketed counting sort (zero global atomics)
    hist_kernel<<<NCHUNK, 256, 0, stream>>>(src, dst, hbD, hbS);
    chunk_scan_kernel<<<NBUCK, NCHUNK, 0, stream>>>(hbD, hbS, pbD, pbS, totD, totS);
    bucket_base_kernel<<<1, 256, 0, stream>>>(totD, totS, baseD, baseS);
    place_kernel<<<NCHUNK, 256, 0, stream>>>(src, dst, baseD, pbD, baseS, pbS, bufD, bufS);
    bucket_dst_kernel<<<NBUCK, NPB, 0, stream>>>(bufD, baseD, totD, csr_src, offsets, inv_in);
    bucket_src_kernel<<<NBUCK, NPB, 0, stream>>>(bufS, baseS, totS, inv_out);

    int dense_blocks  = (N + 31) / 32;
    int gather_blocks = (N + 31) / 32;   // 32 rows per block

    // layer 1: features -> hw(fp16) -> out
    dense_kernel<<<dense_blocks, 256, 0, stream>>>(features, inv_out, W, hw, N);
    gather_kernel<<<gather_blocks, 256, 0, stream>>>((const uint4*)hw, inv_in, offsets, csr_src, b, out, N);

    // layer 2: out -> hw(fp16) -> out
    dense_kernel<<<dense_blocks, 256, 0, stream>>>(out, inv_out, W, hw, N);
    gather_kernel<<<gather_blocks, 256, 0, stream>>>((const uint4*)hw, inv_in, offsets, csr_src, b, out, N);
}